// Round 10
// baseline (126.547 us; speedup 1.0000x reference)
//
#include <hip/hip_runtime.h>
#include <float.h>

#define DIM 64
#define NCODES 512
#define ROWS_PW 32   // rows per 1-wave block (2 row-tiles of 16)

typedef _Float16 half8 __attribute__((ext_vector_type(8)));
typedef float floatx4 __attribute__((ext_vector_type(4)));

// ws layout (float offsets):
//   et    fp32 [512][64]             @ 0
//   norms fp32 [512]                 @ 32768
//   ETh   f16 [8 chunk][512 k][8]    @ 33280
//   ETl   f16 [8 chunk][512 k][8]    @ 49664
#define WS_NORMS 32768
#define WS_ETH   33280
#define WS_ETL   49664

// Prep: transpose emb (D,K) -> fp32 et (K,D); norms; f16 hi/lo tables in
// [chunk][code] layout. Scaled lo split: el' = f16((e - f16(e)) * 2048).
__global__ __launch_bounds__(256) void vq_prep(const float* __restrict__ emb,
                                               float* __restrict__ ws,
                                               float* __restrict__ loss_slot) {
  __shared__ float T[64][65];
  const int tid = threadIdx.x;
  const int k0 = blockIdx.x * 64;
  if (blockIdx.x == 0 && tid == 0) loss_slot[0] = 0.0f;
#pragma unroll
  for (int j = 0; j < 16; ++j) {
    const int d = (tid >> 6) + j * 4;
    const int kl = tid & 63;
    T[d][kl] = emb[d * NCODES + k0 + kl];
  }
  __syncthreads();
  float* et = ws;
  float* norms = ws + WS_NORMS;
#pragma unroll
  for (int j = 0; j < 4; ++j) {
    const int f = tid + j * 256;
    const int kl = f >> 4;
    const int d4 = (f & 15) << 2;
    float4 q;
    q.x = T[d4 + 0][kl]; q.y = T[d4 + 1][kl];
    q.z = T[d4 + 2][kl]; q.w = T[d4 + 3][kl];
    *(float4*)&et[(size_t)(k0 + kl) * DIM + d4] = q;
  }
  if (tid < 64) {
    float s = 0.0f;
#pragma unroll
    for (int d = 0; d < DIM; ++d) s = fmaf(T[d][tid], T[d][tid], s);
    norms[k0 + tid] = s;
  }
  _Float16* eth = (_Float16*)(ws + WS_ETH);
  _Float16* etl = (_Float16*)(ws + WS_ETL);
#pragma unroll
  for (int i = 0; i < 4; ++i) {
    const int g = i * 256 + tid;
    const int split = g >> 9;
    const int h = (g >> 6) & 7;
    const int kl = g & 63;
    const int k = k0 + kl;
    half8 hv;
#pragma unroll
    for (int di = 0; di < 8; ++di) {
      const float v = T[h * 8 + di][kl];
      const _Float16 eh = (_Float16)v;
      const _Float16 el = (_Float16)((v - (float)eh) * 2048.0f);
      hv[di] = split ? el : eh;
    }
    *(half8*)((split ? etl : eth) + ((size_t)h * 512 + k) * 8) = hv;
  }
}

// Main: ONE wave per block, 32 rows (2 row-tiles), all 512 codes, no barriers,
// prefetch distance 2 (r9's pipeline) + 2048 blocks = 8 waves/CU (r8's
// residency). r8/r9 lesson: time ~ per-wave-stall / resident-waves — this
// round stacks both fixes for the first time.
__global__ __launch_bounds__(64) void vq_main(const float* __restrict__ x,
                                              const float* __restrict__ ws,
                                              float* __restrict__ out,
                                              float* __restrict__ loss,
                                              float lscale) {
  __shared__ int sfk[ROWS_PW];

  const float* __restrict__ et = ws;
  const float* __restrict__ norms = ws + WS_NORMS;
  const _Float16* __restrict__ gh = (const _Float16*)(ws + WS_ETH);
  const _Float16* __restrict__ gl = (const _Float16*)(ws + WS_ETL);

  const int lane = threadIdx.x;
  const int col = lane & 15;
  const int quad = lane >> 4;
  const int row0 = blockIdx.x * ROWS_PW;

  // A-frags (A[m=lane&15][k=quad*8+j], round-7-verified): 2 row-tiles x
  // 2 ksteps, f16 hi + scaled lo; exact fp32 ||x||^2 alongside.
  half8 ah[2][2], al[2][2];
  float xn[2];
#pragma unroll
  for (int rt = 0; rt < 2; ++rt) {
    xn[rt] = 0.0f;
#pragma unroll
    for (int ks = 0; ks < 2; ++ks) {
      const float4* xp = (const float4*)x +
                         (size_t)(row0 + rt * 16 + col) * 16 + ks * 8 + quad * 2;
      const float4 f0 = xp[0], f1 = xp[1];
      const float f[8] = {f0.x, f0.y, f0.z, f0.w, f1.x, f1.y, f1.z, f1.w};
#pragma unroll
      for (int j = 0; j < 8; ++j) {
        const float v = f[j];
        xn[rt] = fmaf(v, v, xn[rt]);
        const _Float16 h = (_Float16)v;
        ah[rt][ks][j] = h;
        al[rt][ks][j] = (_Float16)((v - (float)h) * 2048.0f);
      }
    }
    xn[rt] += __shfl_xor(xn[rt], 16);  // sum quads -> full row norm
    xn[rt] += __shfl_xor(xn[rt], 32);
  }

  // Per-lane B-frag base pointers: chunk (ks*4+quad), code col.
  const _Float16* ph0 = gh + ((size_t)(0 + quad) * 512 + col) * 8;
  const _Float16* ph1 = gh + ((size_t)(4 + quad) * 512 + col) * 8;
  const _Float16* pl0 = gl + ((size_t)(0 + quad) * 512 + col) * 8;
  const _Float16* pl1 = gl + ((size_t)(4 + quad) * 512 + col) * 8;

  float best[2][4];
  int bk[2][4];
#pragma unroll
  for (int rt = 0; rt < 2; ++rt)
#pragma unroll
    for (int r = 0; r < 4; ++r) { best[rt][r] = FLT_MAX; bk[rt][r] = 0; }

  // Rotating buffers: b0 = even tile, b1 = odd tile. Preload tiles 0,1.
  half8 b0h0 = *(const half8*)(ph0), b0h1 = *(const half8*)(ph1);
  half8 b0l0 = *(const half8*)(pl0), b0l1 = *(const half8*)(pl1);
  float n0k = norms[col];
  half8 b1h0 = *(const half8*)(ph0 + 128), b1h1 = *(const half8*)(ph1 + 128);
  half8 b1l0 = *(const half8*)(pl0 + 128), b1l1 = *(const half8*)(pl1 + 128);
  float n1k = norms[16 + col];

#pragma unroll 1
  for (int ct = 0; ct < 32; ct += 2) {
    // ---- prefetch tile ct+2 (clamped: harmless re-read of tile 31) ----
    const int p0 = (ct + 2 < 32) ? (ct + 2) : 31;
    const int o0 = p0 * 128;
    const half8 t0h0 = *(const half8*)(ph0 + o0), t0h1 = *(const half8*)(ph1 + o0);
    const half8 t0l0 = *(const half8*)(pl0 + o0), t0l1 = *(const half8*)(pl1 + o0);
    const float tn0 = norms[p0 * 16 + col];
    // ---- compute tile ct from b0 ----
    {
      const int k = ct * 16 + col;
#pragma unroll
      for (int rt = 0; rt < 2; ++rt) {
        floatx4 hh = {0.f, 0.f, 0.f, 0.f};
        floatx4 cr0 = {0.f, 0.f, 0.f, 0.f}, cr1 = {0.f, 0.f, 0.f, 0.f};
        hh = __builtin_amdgcn_mfma_f32_16x16x32_f16(ah[rt][0], b0h0, hh, 0, 0, 0);
        hh = __builtin_amdgcn_mfma_f32_16x16x32_f16(ah[rt][1], b0h1, hh, 0, 0, 0);
        cr0 = __builtin_amdgcn_mfma_f32_16x16x32_f16(al[rt][0], b0h0, cr0, 0, 0, 0);
        cr0 = __builtin_amdgcn_mfma_f32_16x16x32_f16(ah[rt][0], b0l0, cr0, 0, 0, 0);
        cr1 = __builtin_amdgcn_mfma_f32_16x16x32_f16(al[rt][1], b0h1, cr1, 0, 0, 0);
        cr1 = __builtin_amdgcn_mfma_f32_16x16x32_f16(ah[rt][1], b0l1, cr1, 0, 0, 0);
#pragma unroll
        for (int r = 0; r < 4; ++r) {
          const float s = fmaf(cr0[r] + cr1[r], 4.8828125e-4f, hh[r]);
          const float dist = fmaf(s, -2.0f, n0k);  // ||x||^2 dropped
          if (dist < best[rt][r]) { best[rt][r] = dist; bk[rt][r] = k; }
        }
      }
    }
    // ---- prefetch tile ct+3 (clamped) ----
    const int p1 = (ct + 3 < 32) ? (ct + 3) : 31;
    const int o1 = p1 * 128;
    const half8 t1h0 = *(const half8*)(ph0 + o1), t1h1 = *(const half8*)(ph1 + o1);
    const half8 t1l0 = *(const half8*)(pl0 + o1), t1l1 = *(const half8*)(pl1 + o1);
    const float tn1 = norms[p1 * 16 + col];
    // ---- compute tile ct+1 from b1 ----
    {
      const int k = (ct + 1) * 16 + col;
#pragma unroll
      for (int rt = 0; rt < 2; ++rt) {
        floatx4 hh = {0.f, 0.f, 0.f, 0.f};
        floatx4 cr0 = {0.f, 0.f, 0.f, 0.f}, cr1 = {0.f, 0.f, 0.f, 0.f};
        hh = __builtin_amdgcn_mfma_f32_16x16x32_f16(ah[rt][0], b1h0, hh, 0, 0, 0);
        hh = __builtin_amdgcn_mfma_f32_16x16x32_f16(ah[rt][1], b1h1, hh, 0, 0, 0);
        cr0 = __builtin_amdgcn_mfma_f32_16x16x32_f16(al[rt][0], b1h0, cr0, 0, 0, 0);
        cr0 = __builtin_amdgcn_mfma_f32_16x16x32_f16(ah[rt][0], b1l0, cr0, 0, 0, 0);
        cr1 = __builtin_amdgcn_mfma_f32_16x16x32_f16(al[rt][1], b1h1, cr1, 0, 0, 0);
        cr1 = __builtin_amdgcn_mfma_f32_16x16x32_f16(ah[rt][1], b1l1, cr1, 0, 0, 0);
#pragma unroll
        for (int r = 0; r < 4; ++r) {
          const float s = fmaf(cr0[r] + cr1[r], 4.8828125e-4f, hh[r]);
          const float dist = fmaf(s, -2.0f, n1k);
          if (dist < best[rt][r]) { best[rt][r] = dist; bk[rt][r] = k; }
        }
      }
    }
    // rotate
    b0h0 = t0h0; b0h1 = t0h1; b0l0 = t0l0; b0l1 = t0l1; n0k = tn0;
    b1h0 = t1h0; b1h1 = t1h1; b1l0 = t1l0; b1l1 = t1l1; n1k = tn1;
  }

  // Reduce over the 16 col-lanes (xor butterfly); tie -> smaller k (np.argmin)
#pragma unroll
  for (int off = 1; off < 16; off <<= 1) {
#pragma unroll
    for (int rt = 0; rt < 2; ++rt)
#pragma unroll
      for (int r = 0; r < 4; ++r) {
        const float ob = __shfl_xor(best[rt][r], off);
        const int ok = __shfl_xor(bk[rt][r], off);
        if (ob < best[rt][r] || (ob == best[rt][r] && ok < bk[rt][r])) {
          best[rt][r] = ob; bk[rt][r] = ok;
        }
      }
  }

  // Loss: ||x-q||^2 = best + ||x||^2
  float ls = 0.0f;
#pragma unroll
  for (int rt = 0; rt < 2; ++rt)
#pragma unroll
    for (int r = 0; r < 4; ++r) {
      const int m = quad * 4 + r;
      const float xnm = __shfl(xn[rt], (lane & 48) | m, 64);
      ls += best[rt][r] + xnm;
    }
  ls = (col == 0) ? ls : 0.0f;
  ls += __shfl_xor(ls, 16);
  ls += __shfl_xor(ls, 32);
  if (lane == 0) atomicAdd(loss, ls * lscale);

  if (col == 0) {
#pragma unroll
    for (int rt = 0; rt < 2; ++rt)
#pragma unroll
      for (int r = 0; r < 4; ++r)
        sfk[rt * 16 + quad * 4 + r] = bk[rt][r];
  }
  __syncthreads();  // single-wave block: cheap

  // Epilogue: gather winning fp32 code rows (et is L2-hot), coalesced stores
  {
    float* __restrict__ o = out + (size_t)row0 * DIM;
#pragma unroll
    for (int j = 0; j < 8; ++j) {
      const int f = lane + j * 64;   // 0..511
      const int r = f >> 4;          // row 0..31
      const int c = (f & 15) << 2;   // col 0..60
      const int k = sfk[r];
      *(float4*)&o[(size_t)r * DIM + c] = *(const float4*)&et[(size_t)k * DIM + c];
    }
  }
}

extern "C" void kernel_launch(void* const* d_in, const int* in_sizes, int n_in,
                              void* d_out, int out_size, void* d_ws, size_t ws_size,
                              hipStream_t stream) {
  const float* x = (const float*)d_in[0];    // (64,32,32,64) fp32
  const float* emb = (const float*)d_in[1];  // (64,512) fp32
  float* out = (float*)d_out;                // out (4194304) + loss (1)

  const int nrows = in_sizes[0] / DIM;       // 65536
  float* ws = (float*)d_ws;                  // 264 KB used
  float* loss = out + (out_size - 1);

  vq_prep<<<NCODES / 64, 256, 0, stream>>>(emb, ws, loss);

  const float lscale = 1.25f / (float)(nrows * DIM);  // (1+beta)/numel
  vq_main<<<nrows / ROWS_PW, 64, 0, stream>>>(x, ws, out, loss, lscale);
}

// Round 11
// 115.459 us; speedup vs baseline: 1.0960x; 1.0960x over previous
//
#include <hip/hip_runtime.h>
#include <float.h>

#define DIM 64
#define NCODES 512
#define ROWS_PB 32   // rows per block (2 row-tiles of 16, shared by 4 waves)
#define WPB 4        // waves per block; wave w scans codes [128w, 128w+128)
#define TPW 8        // 16-code tiles per wave

typedef _Float16 half8 __attribute__((ext_vector_type(8)));
typedef float floatx4 __attribute__((ext_vector_type(4)));

// ws layout (float offsets):
//   et    fp32 [512][64]             @ 0
//   norms fp32 [512]                 @ 32768
//   ETh   f16 [8 chunk][512 k][8]    @ 33280
//   ETl   f16 [8 chunk][512 k][8]    @ 49664
#define WS_NORMS 32768
#define WS_ETH   33280
#define WS_ETL   49664

// Prep: transpose emb (D,K) -> fp32 et (K,D); norms; f16 hi/lo tables in
// [chunk][code] layout. Scaled lo split: el' = f16((e - f16(e)) * 2048).
__global__ __launch_bounds__(256) void vq_prep(const float* __restrict__ emb,
                                               float* __restrict__ ws,
                                               float* __restrict__ loss_slot) {
  __shared__ float T[64][65];
  const int tid = threadIdx.x;
  const int k0 = blockIdx.x * 64;
  if (blockIdx.x == 0 && tid == 0) loss_slot[0] = 0.0f;
#pragma unroll
  for (int j = 0; j < 16; ++j) {
    const int d = (tid >> 6) + j * 4;
    const int kl = tid & 63;
    T[d][kl] = emb[d * NCODES + k0 + kl];
  }
  __syncthreads();
  float* et = ws;
  float* norms = ws + WS_NORMS;
#pragma unroll
  for (int j = 0; j < 4; ++j) {
    const int f = tid + j * 256;
    const int kl = f >> 4;
    const int d4 = (f & 15) << 2;
    float4 q;
    q.x = T[d4 + 0][kl]; q.y = T[d4 + 1][kl];
    q.z = T[d4 + 2][kl]; q.w = T[d4 + 3][kl];
    *(float4*)&et[(size_t)(k0 + kl) * DIM + d4] = q;
  }
  if (tid < 64) {
    float s = 0.0f;
#pragma unroll
    for (int d = 0; d < DIM; ++d) s = fmaf(T[d][tid], T[d][tid], s);
    norms[k0 + tid] = s;
  }
  _Float16* eth = (_Float16*)(ws + WS_ETH);
  _Float16* etl = (_Float16*)(ws + WS_ETL);
#pragma unroll
  for (int i = 0; i < 4; ++i) {
    const int g = i * 256 + tid;
    const int split = g >> 9;
    const int h = (g >> 6) & 7;
    const int kl = g & 63;
    const int k = k0 + kl;
    half8 hv;
#pragma unroll
    for (int di = 0; di < 8; ++di) {
      const float v = T[h * 8 + di][kl];
      const _Float16 eh = (_Float16)v;
      const _Float16 el = (_Float16)((v - (float)eh) * 2048.0f);
      hv[di] = split ? el : eh;
    }
    *(half8*)((split ? etl : eth) + ((size_t)h * 512 + k) * 8) = hv;
  }
}

// Main: 2048 blocks x 4 waves; 32 rows/block (all waves same rows), 4-way
// code split, prefetch-2 k-loop (r9-verified). r8/r9/r10 lesson: every
// design so far ran 1-2 waves/SIMD and sat ~80% idle; this fields 8192
// waves (up to 32/CU) so stalls interleave. launch_bounds(256,4) caps
// VGPR at 128 to guarantee >=4 waves/SIMD.
__global__ __launch_bounds__(256, 4) void vq_main(const float* __restrict__ x,
                                                  const float* __restrict__ ws,
                                                  float* __restrict__ out,
                                                  float* __restrict__ loss,
                                                  float lscale) {
  __shared__ float sbest[WPB][ROWS_PB];
  __shared__ int sidx[WPB][ROWS_PB];
  __shared__ float sxn[ROWS_PB];
  __shared__ int sfk[ROWS_PB];

  const float* __restrict__ et = ws;
  const float* __restrict__ norms = ws + WS_NORMS;
  const _Float16* __restrict__ gh = (const _Float16*)(ws + WS_ETH);
  const _Float16* __restrict__ gl = (const _Float16*)(ws + WS_ETL);

  const int tid = threadIdx.x;
  const int lane = tid & 63;
  const int wid = tid >> 6;          // 0..3
  const int col = lane & 15;
  const int quad = lane >> 4;
  const int row0 = blockIdx.x * ROWS_PB;
  const int kbase = __builtin_amdgcn_readfirstlane(wid * 128);

  // A-frags (A[m=lane&15][k=quad*8+j], round-7-verified): 2 row-tiles x
  // 2 ksteps, f16 hi + scaled lo; exact fp32 ||x||^2 alongside.
  // All 4 waves load the same 32 rows (x tile is L2-hot).
  half8 ah[2][2], al[2][2];
  float xn[2];
#pragma unroll
  for (int rt = 0; rt < 2; ++rt) {
    xn[rt] = 0.0f;
#pragma unroll
    for (int ks = 0; ks < 2; ++ks) {
      const float4* xp = (const float4*)x +
                         (size_t)(row0 + rt * 16 + col) * 16 + ks * 8 + quad * 2;
      const float4 f0 = xp[0], f1 = xp[1];
      const float f[8] = {f0.x, f0.y, f0.z, f0.w, f1.x, f1.y, f1.z, f1.w};
#pragma unroll
      for (int j = 0; j < 8; ++j) {
        const float v = f[j];
        xn[rt] = fmaf(v, v, xn[rt]);
        const _Float16 h = (_Float16)v;
        ah[rt][ks][j] = h;
        al[rt][ks][j] = (_Float16)((v - (float)h) * 2048.0f);
      }
    }
    xn[rt] += __shfl_xor(xn[rt], 16);  // sum quads -> full row norm
    xn[rt] += __shfl_xor(xn[rt], 32);
  }

  // Per-lane B-frag base pointers: chunk (ks*4+quad), code (kbase+col).
  const _Float16* ph0 = gh + ((size_t)(0 + quad) * 512 + kbase + col) * 8;
  const _Float16* ph1 = gh + ((size_t)(4 + quad) * 512 + kbase + col) * 8;
  const _Float16* pl0 = gl + ((size_t)(0 + quad) * 512 + kbase + col) * 8;
  const _Float16* pl1 = gl + ((size_t)(4 + quad) * 512 + kbase + col) * 8;

  float best[2][4];
  int bk[2][4];
#pragma unroll
  for (int rt = 0; rt < 2; ++rt)
#pragma unroll
    for (int r = 0; r < 4; ++r) { best[rt][r] = FLT_MAX; bk[rt][r] = 0; }

  // Rotating buffers: b0 = even tile, b1 = odd tile. Preload tiles 0,1.
  half8 b0h0 = *(const half8*)(ph0), b0h1 = *(const half8*)(ph1);
  half8 b0l0 = *(const half8*)(pl0), b0l1 = *(const half8*)(pl1);
  float n0k = norms[kbase + col];
  half8 b1h0 = *(const half8*)(ph0 + 128), b1h1 = *(const half8*)(ph1 + 128);
  half8 b1l0 = *(const half8*)(pl0 + 128), b1l1 = *(const half8*)(pl1 + 128);
  float n1k = norms[kbase + 16 + col];

#pragma unroll 1
  for (int ct = 0; ct < TPW; ct += 2) {
    // ---- prefetch tile ct+2 (clamped: harmless re-read of last tile) ----
    const int p0 = (ct + 2 < TPW) ? (ct + 2) : (TPW - 1);
    const int o0 = p0 * 128;
    const half8 t0h0 = *(const half8*)(ph0 + o0), t0h1 = *(const half8*)(ph1 + o0);
    const half8 t0l0 = *(const half8*)(pl0 + o0), t0l1 = *(const half8*)(pl1 + o0);
    const float tn0 = norms[kbase + p0 * 16 + col];
    // ---- compute tile ct from b0 ----
    {
      const int k = kbase + ct * 16 + col;
#pragma unroll
      for (int rt = 0; rt < 2; ++rt) {
        floatx4 hh = {0.f, 0.f, 0.f, 0.f};
        floatx4 cr0 = {0.f, 0.f, 0.f, 0.f}, cr1 = {0.f, 0.f, 0.f, 0.f};
        hh = __builtin_amdgcn_mfma_f32_16x16x32_f16(ah[rt][0], b0h0, hh, 0, 0, 0);
        hh = __builtin_amdgcn_mfma_f32_16x16x32_f16(ah[rt][1], b0h1, hh, 0, 0, 0);
        cr0 = __builtin_amdgcn_mfma_f32_16x16x32_f16(al[rt][0], b0h0, cr0, 0, 0, 0);
        cr0 = __builtin_amdgcn_mfma_f32_16x16x32_f16(ah[rt][0], b0l0, cr0, 0, 0, 0);
        cr1 = __builtin_amdgcn_mfma_f32_16x16x32_f16(al[rt][1], b0h1, cr1, 0, 0, 0);
        cr1 = __builtin_amdgcn_mfma_f32_16x16x32_f16(ah[rt][1], b0l1, cr1, 0, 0, 0);
#pragma unroll
        for (int r = 0; r < 4; ++r) {
          const float s = fmaf(cr0[r] + cr1[r], 4.8828125e-4f, hh[r]);
          const float dist = fmaf(s, -2.0f, n0k);  // ||x||^2 dropped
          if (dist < best[rt][r]) { best[rt][r] = dist; bk[rt][r] = k; }
        }
      }
    }
    // ---- prefetch tile ct+3 (clamped) ----
    const int p1 = (ct + 3 < TPW) ? (ct + 3) : (TPW - 1);
    const int o1 = p1 * 128;
    const half8 t1h0 = *(const half8*)(ph0 + o1), t1h1 = *(const half8*)(ph1 + o1);
    const half8 t1l0 = *(const half8*)(pl0 + o1), t1l1 = *(const half8*)(pl1 + o1);
    const float tn1 = norms[kbase + p1 * 16 + col];
    // ---- compute tile ct+1 from b1 ----
    {
      const int k = kbase + (ct + 1) * 16 + col;
#pragma unroll
      for (int rt = 0; rt < 2; ++rt) {
        floatx4 hh = {0.f, 0.f, 0.f, 0.f};
        floatx4 cr0 = {0.f, 0.f, 0.f, 0.f}, cr1 = {0.f, 0.f, 0.f, 0.f};
        hh = __builtin_amdgcn_mfma_f32_16x16x32_f16(ah[rt][0], b1h0, hh, 0, 0, 0);
        hh = __builtin_amdgcn_mfma_f32_16x16x32_f16(ah[rt][1], b1h1, hh, 0, 0, 0);
        cr0 = __builtin_amdgcn_mfma_f32_16x16x32_f16(al[rt][0], b1h0, cr0, 0, 0, 0);
        cr0 = __builtin_amdgcn_mfma_f32_16x16x32_f16(ah[rt][0], b1l0, cr0, 0, 0, 0);
        cr1 = __builtin_amdgcn_mfma_f32_16x16x32_f16(al[rt][1], b1h1, cr1, 0, 0, 0);
        cr1 = __builtin_amdgcn_mfma_f32_16x16x32_f16(ah[rt][1], b1l1, cr1, 0, 0, 0);
#pragma unroll
        for (int r = 0; r < 4; ++r) {
          const float s = fmaf(cr0[r] + cr1[r], 4.8828125e-4f, hh[r]);
          const float dist = fmaf(s, -2.0f, n1k);
          if (dist < best[rt][r]) { best[rt][r] = dist; bk[rt][r] = k; }
        }
      }
    }
    // rotate
    b0h0 = t0h0; b0h1 = t0h1; b0l0 = t0l0; b0l1 = t0l1; n0k = tn0;
    b1h0 = t1h0; b1h1 = t1h1; b1l0 = t1l0; b1l1 = t1l1; n1k = tn1;
  }

  // Reduce over the 16 col-lanes (xor butterfly); tie -> smaller k (np.argmin)
#pragma unroll
  for (int off = 1; off < 16; off <<= 1) {
#pragma unroll
    for (int rt = 0; rt < 2; ++rt)
#pragma unroll
      for (int r = 0; r < 4; ++r) {
        const float ob = __shfl_xor(best[rt][r], off);
        const int ok = __shfl_xor(bk[rt][r], off);
        if (ob < best[rt][r] || (ob == best[rt][r] && ok < bk[rt][r])) {
          best[rt][r] = ob; bk[rt][r] = ok;
        }
      }
  }

  // Publish per-wave results; wave 0 quad 0 publishes row norms
  if (col == 0) {
#pragma unroll
    for (int rt = 0; rt < 2; ++rt)
#pragma unroll
      for (int r = 0; r < 4; ++r) {
        sbest[wid][rt * 16 + quad * 4 + r] = best[rt][r];
        sidx[wid][rt * 16 + quad * 4 + r] = bk[rt][r];
      }
  }
  if (wid == 0 && quad == 0) {
    sxn[col] = xn[0];
    sxn[16 + col] = xn[1];
  }
  __syncthreads();

  // Cross-wave combine (ascending wave = ascending k; strict < keeps min k)
  float lsum = 0.0f;
  if (wid == 0) {
    if (lane < ROWS_PB) {
      float fb = sbest[0][lane];
      int fk = sidx[0][lane];
#pragma unroll
      for (int w = 1; w < WPB; ++w) {
        const float b = sbest[w][lane];
        if (b < fb) { fb = b; fk = sidx[w][lane]; }
      }
      sfk[lane] = fk;
      lsum = fb + sxn[lane];  // ||x-q||^2 = best + ||x||^2
    }
#pragma unroll
    for (int off = 32; off > 0; off >>= 1) lsum += __shfl_down(lsum, off, 64);
    if (lane == 0) atomicAdd(loss, lsum * lscale);
  }
  __syncthreads();

  // Epilogue: gather winning fp32 code rows (et is L2-hot), coalesced stores
  {
    float* __restrict__ o = out + (size_t)row0 * DIM;
#pragma unroll
    for (int j = 0; j < 2; ++j) {
      const int f = tid + j * 256;   // 0..511
      const int r = f >> 4;          // row 0..31
      const int c = (f & 15) << 2;   // col 0..60
      const int k = sfk[r];
      *(float4*)&o[(size_t)r * DIM + c] = *(const float4*)&et[(size_t)k * DIM + c];
    }
  }
}

extern "C" void kernel_launch(void* const* d_in, const int* in_sizes, int n_in,
                              void* d_out, int out_size, void* d_ws, size_t ws_size,
                              hipStream_t stream) {
  const float* x = (const float*)d_in[0];    // (64,32,32,64) fp32
  const float* emb = (const float*)d_in[1];  // (64,512) fp32
  float* out = (float*)d_out;                // out (4194304) + loss (1)

  const int nrows = in_sizes[0] / DIM;       // 65536
  float* ws = (float*)d_ws;                  // 264 KB used
  float* loss = out + (out_size - 1);

  vq_prep<<<NCODES / 64, 256, 0, stream>>>(emb, ws, loss);

  const float lscale = 1.25f / (float)(nrows * DIM);  // (1+beta)/numel
  vq_main<<<nrows / ROWS_PB, 256, 0, stream>>>(x, ws, out, loss, lscale);
}